// Round 11
// baseline (395.686 us; speedup 1.0000x reference)
//
#include <hip/hip_runtime.h>
#include <hip/hip_bf16.h>

// out[m,b,:] = kv[m,b,:] @ W + bo + query[b,:],  W = (Wo@Wv) row o, col d
// (softmax over size-1 axis == 1 -> ones; q/k/Wq/Wk dead). f32 output.
// K1: Cw = Wo@Wv, MFMA bf16, 64x64 tiles, 256 blocks (~4us, proven r9).
// K2: NO-LDS / NO-BARRIER direct-fragment GEMM. The 16x16x32 fragment layout
//     (lane l: row=l&15, k=(l>>4)*8..+7, PROVEN via LDS path r7-r10) is
//     contiguous in global memory for both operands -> load fragments
//     straight from global with immediate-offset loads; cvt A f32->bf16 in
//     reg. B (Cw, 2MB) is pure-L2; A dup (2x per wc-pair) is L1-absorbed.
//     Removes every barrier: compiler pipelines loads freely across K.

typedef __attribute__((ext_vector_type(4))) float f32x4;
typedef __attribute__((ext_vector_type(8))) short short8;

#define D_MODEL 1024
#define BATCH   4096
#define M_ROWS  32768   // 8 * 4096

__device__ __forceinline__ short f2bf(float f) {
    union { float f; unsigned u; } x; x.f = f;
    unsigned r = (x.u + 0x7fffu + ((x.u >> 16) & 1u)) >> 16;   // RNE
    return (short)r;
}

__device__ __forceinline__ unsigned bfpk(float lo, float hi) {
    __hip_bfloat162 h = __float22bfloat162_rn(make_float2(lo, hi));  // v_cvt_pk_bf16_f32
    unsigned u; __builtin_memcpy(&u, &h, 4); return u;
}

__device__ __forceinline__ short8 cvt8(float4 a, float4 b) {
    union { unsigned u[4]; short8 s; } r;
    r.u[0] = bfpk(a.x, a.y);
    r.u[1] = bfpk(a.z, a.w);
    r.u[2] = bfpk(b.x, b.y);
    r.u[3] = bfpk(b.z, b.w);
    return r.s;
}

// ---------------- Kernel 1: fuse weights Cw = Wo @ Wv (bf16, MFMA, 64x64) ----------------
__global__ __launch_bounds__(256) void fuse_w_kernel(
        const float* __restrict__ Wo, const float* __restrict__ Wv,
        short* __restrict__ Cw) {
    __shared__ __align__(16) short Ash[64][32];   // Wo tile  [o][e]
    __shared__ __align__(16) short Bsh[64][32];   // Wv tile transposed: [d][e]
    const int t = threadIdx.x;
    const int lane = t & 63;
    const int w = t >> 6;
    const int wr = w >> 1, wc = w & 1;
    const int brow = blockIdx.y * 64;   // o
    const int bcol = blockIdx.x * 64;   // d

    f32x4 acc[2][2];
#pragma unroll
    for (int m = 0; m < 2; ++m)
#pragma unroll
        for (int n = 0; n < 2; ++n) acc[m][n] = (f32x4)(0.0f);

    for (int kt = 0; kt < 32; ++kt) {
        const float* ga = Wo + (size_t)(brow + (t >> 2)) * D_MODEL + kt * 32 + (t & 3) * 8;
        float4 a0 = *(const float4*)ga;
        float4 a1 = *(const float4*)(ga + 4);
        float4 bv[2];
#pragma unroll
        for (int j = 0; j < 2; ++j) {
            int lin = j * 256 + t;
            int e = lin >> 4, c4 = lin & 15;
            bv[j] = *(const float4*)(Wv + (size_t)(kt * 32 + e) * D_MODEL + bcol + c4 * 4);
        }
        *reinterpret_cast<short8*>(&Ash[t >> 2][(t & 3) * 8]) = cvt8(a0, a1);
#pragma unroll
        for (int j = 0; j < 2; ++j) {
            int lin = j * 256 + t;
            int e = lin >> 4, c4 = lin & 15;
            int d = c4 * 4;
            Bsh[d + 0][e] = f2bf(bv[j].x);
            Bsh[d + 1][e] = f2bf(bv[j].y);
            Bsh[d + 2][e] = f2bf(bv[j].z);
            Bsh[d + 3][e] = f2bf(bv[j].w);
        }
        __syncthreads();
        {
            const int r = lane & 15, q = lane >> 4;
            short8 af[2], bfr[2];
#pragma unroll
            for (int m = 0; m < 2; ++m)
                af[m] = *reinterpret_cast<const short8*>(&Ash[wr * 32 + m * 16 + r][q * 8]);
#pragma unroll
            for (int n = 0; n < 2; ++n)
                bfr[n] = *reinterpret_cast<const short8*>(&Bsh[wc * 32 + n * 16 + r][q * 8]);
#pragma unroll
            for (int m = 0; m < 2; ++m)
#pragma unroll
                for (int n = 0; n < 2; ++n)
                    acc[m][n] = __builtin_amdgcn_mfma_f32_16x16x32_bf16(
                        af[m], bfr[n], acc[m][n], 0, 0, 0);
        }
        __syncthreads();
    }

    const int r = lane & 15, q = lane >> 4;
#pragma unroll
    for (int m = 0; m < 2; ++m)
#pragma unroll
        for (int n = 0; n < 2; ++n)
#pragma unroll
            for (int j = 0; j < 4; ++j) {
                int o = brow + wr * 32 + m * 16 + q * 4 + j;     // C/D: row=(l>>4)*4+j
                int d = bcol + wc * 32 + n * 16 + r;             //      col=l&15
                Cw[(size_t)o * D_MODEL + d] = f2bf(acc[m][n][j]);
            }
}

// ---------------- Kernel 2: out = kv @ Cw.T + bo + query — direct-fragment, barrier-free ----------------
__global__ __launch_bounds__(256) void attn_gemm_kernel(
        const float* __restrict__ kv, const float* __restrict__ query,
        const short* __restrict__ Cw, const float* __restrict__ bo,
        float* __restrict__ out) {
    const int t = threadIdx.x;
    const int lane = t & 63;
    const int w = t >> 6;
    const int wr = w >> 1, wc = w & 1;
    const int r = lane & 15, q = lane >> 4;

    // XCD swizzle: XCD = L % 8. All 8 o-tiles of one row-tile share L%8 ->
    // same XCD, co-resident -> kv L2-reused (proven r8: FETCH 574->141 MB).
    const int L = blockIdx.x;
    const int x = L & 7, j5 = L >> 3;
    const int bx = j5 & 7;                   // o-tile (0..7)
    const int rt = (j5 >> 3) * 8 + x;        // row-tile (0..255)
    const int brow = rt * 128;

    f32x4 acc[4][4];
#pragma unroll
    for (int m = 0; m < 4; ++m)
#pragma unroll
        for (int n = 0; n < 4; ++n) acc[m][n] = (f32x4)(0.0f);

    // Per-lane fragment base pointers; kt advances by immediate offsets
    // (A: kt*128B <= 3984, B: kt*64B <= 1984 — both fit the 13-bit imm).
    const float* aptr[4];
#pragma unroll
    for (int m = 0; m < 4; ++m)
        aptr[m] = kv + (size_t)(brow + wr * 64 + m * 16 + r) * D_MODEL + q * 8;
    const short* bptr[4];
#pragma unroll
    for (int n = 0; n < 4; ++n)
        bptr[n] = Cw + (size_t)(bx * 128 + wc * 64 + n * 16 + r) * D_MODEL + q * 8;

#pragma unroll 2
    for (int kt = 0; kt < 32; ++kt) {
        short8 af[4], bfr[4];
#pragma unroll
        for (int m = 0; m < 4; ++m) {
            float4 lo = *(const float4*)(aptr[m] + kt * 32);
            float4 hi = *(const float4*)(aptr[m] + kt * 32 + 4);
            af[m] = cvt8(lo, hi);
        }
#pragma unroll
        for (int n = 0; n < 4; ++n)
            bfr[n] = *reinterpret_cast<const short8*>(bptr[n] + kt * 32);
#pragma unroll
        for (int m = 0; m < 4; ++m)
#pragma unroll
            for (int n = 0; n < 4; ++n)
                acc[m][n] = __builtin_amdgcn_mfma_f32_16x16x32_bf16(
                    af[m], bfr[n], acc[m][n], 0, 0, 0);
    }

    // epilogue: + bo + query residual, f32 store
#pragma unroll
    for (int n = 0; n < 4; ++n) {
        int o = bx * 128 + wc * 64 + n * 16 + r;
        float bov = bo[o];
#pragma unroll
        for (int m = 0; m < 4; ++m) {
            int gb = brow + wr * 64 + m * 16 + q * 4;
#pragma unroll
            for (int j = 0; j < 4; ++j) {
                int grow = gb + j;
                out[(size_t)grow * D_MODEL + o] =
                    acc[m][n][j] + bov +
                    query[(size_t)(grow & (BATCH - 1)) * D_MODEL + o];
            }
        }
    }
}

extern "C" void kernel_launch(void* const* d_in, const int* in_sizes, int n_in,
                              void* d_out, int out_size, void* d_ws, size_t ws_size,
                              hipStream_t stream) {
    // Robust input classification by element count (falls back to dict order):
    int kv_i = 1, q_i = 0, bo_i = 6;
    int w_i[4] = {2, 3, 4, 5};
    int nw = 0;
    for (int i = 0; i < n_in; ++i) {
        long s = in_sizes[i];
        if (s == 33554432) kv_i = i;
        else if (s == 4194304) q_i = i;
        else if (s == 1024) bo_i = i;
        else if (s == 1048576 && nw < 4) w_i[nw++] = i;
    }
    const float* query = (const float*)d_in[q_i];
    const float* kv    = (const float*)d_in[kv_i];
    const float* Wv    = (const float*)d_in[w_i[2]];
    const float* Wo    = (const float*)d_in[w_i[3]];
    const float* bo    = (const float*)d_in[bo_i];
    short* Cw  = (short*)d_ws;              // 1024*1024 bf16 = 2 MB
    float* out = (float*)d_out;             // f32 output

    fuse_w_kernel<<<dim3(16, 16), dim3(256), 0, stream>>>(Wo, Wv, Cw);
    attn_gemm_kernel<<<dim3(2048), dim3(256), 0, stream>>>(kv, query, Cw, bo, out);
}

// Round 12
// 224.147 us; speedup vs baseline: 1.7653x; 1.7653x over previous
//
#include <hip/hip_runtime.h>
#include <hip/hip_bf16.h>

// out[m,b,:] = kv[m,b,:] @ W + bo + query[b,:],  W = (Wo@Wv) row o, col d
// (softmax over size-1 axis == 1 -> ones; q/k/Wq/Wk dead). f32 output.
// K1: Cw = Wo@Wv, MFMA bf16, 64x64 tiles, 256 blocks (~4us, proven r9).
// K2: m97-structure GEMM — BOTH operands via global_load_lds (A as raw f32
//     bytes, swizzled; B bf16 linear, proven r7-r9), 2 barriers/K-step,
//     compiler-managed waits. f32->bf16 pk-convert in the compute phase.
//     A-tile XOR swizzle (chunk ^= row&7, both-sides: pre-swizzled glds
//     SOURCE + swizzled ds_read; LDS dest linear) kills the 16-way conflict
//     a row-major 128B-stride f32 tile would have.

typedef __attribute__((ext_vector_type(4))) float f32x4;
typedef __attribute__((ext_vector_type(8))) short short8;

#define D_MODEL 1024
#define BATCH   4096
#define M_ROWS  32768   // 8 * 4096

__device__ __forceinline__ short f2bf(float f) {
    union { float f; unsigned u; } x; x.f = f;
    unsigned r = (x.u + 0x7fffu + ((x.u >> 16) & 1u)) >> 16;   // RNE
    return (short)r;
}

__device__ __forceinline__ unsigned bfpk(float lo, float hi) {
    __hip_bfloat162 h = __float22bfloat162_rn(make_float2(lo, hi));  // v_cvt_pk_bf16_f32
    unsigned u; __builtin_memcpy(&u, &h, 4); return u;
}

__device__ __forceinline__ short8 cvt8(float4 a, float4 b) {
    union { unsigned u[4]; short8 s; } r;
    r.u[0] = bfpk(a.x, a.y);
    r.u[1] = bfpk(a.z, a.w);
    r.u[2] = bfpk(b.x, b.y);
    r.u[3] = bfpk(b.z, b.w);
    return r.s;
}

// ---------------- Kernel 1: fuse weights Cw = Wo @ Wv (bf16, MFMA, 64x64) ----------------
__global__ __launch_bounds__(256) void fuse_w_kernel(
        const float* __restrict__ Wo, const float* __restrict__ Wv,
        short* __restrict__ Cw) {
    __shared__ __align__(16) short Ash[64][32];   // Wo tile  [o][e]
    __shared__ __align__(16) short Bsh[64][32];   // Wv tile transposed: [d][e]
    const int t = threadIdx.x;
    const int lane = t & 63;
    const int w = t >> 6;
    const int wr = w >> 1, wc = w & 1;
    const int brow = blockIdx.y * 64;   // o
    const int bcol = blockIdx.x * 64;   // d

    f32x4 acc[2][2];
#pragma unroll
    for (int m = 0; m < 2; ++m)
#pragma unroll
        for (int n = 0; n < 2; ++n) acc[m][n] = (f32x4)(0.0f);

    for (int kt = 0; kt < 32; ++kt) {
        const float* ga = Wo + (size_t)(brow + (t >> 2)) * D_MODEL + kt * 32 + (t & 3) * 8;
        float4 a0 = *(const float4*)ga;
        float4 a1 = *(const float4*)(ga + 4);
        float4 bv[2];
#pragma unroll
        for (int j = 0; j < 2; ++j) {
            int lin = j * 256 + t;
            int e = lin >> 4, c4 = lin & 15;
            bv[j] = *(const float4*)(Wv + (size_t)(kt * 32 + e) * D_MODEL + bcol + c4 * 4);
        }
        *reinterpret_cast<short8*>(&Ash[t >> 2][(t & 3) * 8]) = cvt8(a0, a1);
#pragma unroll
        for (int j = 0; j < 2; ++j) {
            int lin = j * 256 + t;
            int e = lin >> 4, c4 = lin & 15;
            int d = c4 * 4;
            Bsh[d + 0][e] = f2bf(bv[j].x);
            Bsh[d + 1][e] = f2bf(bv[j].y);
            Bsh[d + 2][e] = f2bf(bv[j].z);
            Bsh[d + 3][e] = f2bf(bv[j].w);
        }
        __syncthreads();
        {
            const int r = lane & 15, q = lane >> 4;
            short8 af[2], bfr[2];
#pragma unroll
            for (int m = 0; m < 2; ++m)
                af[m] = *reinterpret_cast<const short8*>(&Ash[wr * 32 + m * 16 + r][q * 8]);
#pragma unroll
            for (int n = 0; n < 2; ++n)
                bfr[n] = *reinterpret_cast<const short8*>(&Bsh[wc * 32 + n * 16 + r][q * 8]);
#pragma unroll
            for (int m = 0; m < 2; ++m)
#pragma unroll
                for (int n = 0; n < 2; ++n)
                    acc[m][n] = __builtin_amdgcn_mfma_f32_16x16x32_bf16(
                        af[m], bfr[n], acc[m][n], 0, 0, 0);
        }
        __syncthreads();
    }

    const int r = lane & 15, q = lane >> 4;
#pragma unroll
    for (int m = 0; m < 2; ++m)
#pragma unroll
        for (int n = 0; n < 2; ++n)
#pragma unroll
            for (int j = 0; j < 4; ++j) {
                int o = brow + wr * 32 + m * 16 + q * 4 + j;     // C/D: row=(l>>4)*4+j
                int d = bcol + wc * 32 + n * 16 + r;             //      col=l&15
                Cw[(size_t)o * D_MODEL + d] = f2bf(acc[m][n][j]);
            }
}

// ---------------- Kernel 2: out = kv @ Cw.T + bo + query — m97 structure ----------------
__global__ __launch_bounds__(256) void attn_gemm_kernel(
        const float* __restrict__ kv, const float* __restrict__ query,
        const short* __restrict__ Cw, const float* __restrict__ bo,
        float* __restrict__ out) {
    // A tile: f32 [128 rows][32 cols] = 16 KB; row = 8 chunks of 16B; chunk
    // index XOR-swizzled with (row&7). LDS dest of glds is linear; the
    // permutation is applied to the global SOURCE address and the ds_read.
    __shared__ __align__(16) float Afs[128][32];
    __shared__ __align__(16) short Bsh[128][32];   // Cw tile [o][32 bf16], linear (r7-r9 proven)
    const int t = threadIdx.x;
    const int lane = t & 63;
    const int w = t >> 6;
    const int wr = w >> 1, wc = w & 1;
    const int r = lane & 15, q = lane >> 4;

    // XCD swizzle: XCD = L % 8; 8 o-tiles of one row-tile share an XCD ->
    // kv L2-reused 8x (proven r8: FETCH 574->141 MB).
    const int L = blockIdx.x;
    const int x = L & 7, j5 = L >> 3;
    const int bx = j5 & 7;                   // o-tile (0..7)
    const int rt = (j5 >> 3) * 8 + x;        // row-tile (0..255)
    const int brow = rt * 128;

    f32x4 acc[4][4];
#pragma unroll
    for (int m = 0; m < 4; ++m)
#pragma unroll
        for (int n = 0; n < 4; ++n) acc[m][n] = (f32x4)(0.0f);

    for (int kt = 0; kt < 32; ++kt) {
        // ---- stage A: 4 glds issues, 16B/lane. LDS byte off = i*4096+t*16
        //      -> row rl = i*32+(t>>3), chunk c = t&7. Source chunk = c^(rl&7).
#pragma unroll
        for (int i = 0; i < 4; ++i) {
            int rl = i * 32 + (t >> 3);
            int cg = (t & 7) ^ (rl & 7);
            const float* g = kv + (size_t)(brow + rl) * D_MODEL + kt * 32 + cg * 4;
            __builtin_amdgcn_global_load_lds(
                (const __attribute__((address_space(1))) void*)g,
                (__attribute__((address_space(3))) void*)
                    ((char*)&Afs[0][0] + i * 4096 + w * 1024),
                16, 0, 0);
        }
        // ---- stage B: 2 glds issues, linear (proven). row rl = i*64+(t>>2),
        //      chunk = t&3 (16B = 8 bf16).
#pragma unroll
        for (int i = 0; i < 2; ++i) {
            int rl = i * 64 + (t >> 2);
            const short* g = Cw + (size_t)(bx * 128 + rl) * D_MODEL + kt * 32 + (t & 3) * 8;
            __builtin_amdgcn_global_load_lds(
                (const __attribute__((address_space(1))) void*)g,
                (__attribute__((address_space(3))) void*)
                    ((char*)&Bsh[0][0] + i * 4096 + w * 1024),
                16, 0, 0);
        }
        __syncthreads();   // drains vmcnt (compiler), LDS valid
        {
            short8 af[4], bfr[4];
#pragma unroll
            for (int m = 0; m < 4; ++m) {
                int rl = wr * 64 + m * 16 + r;
                int c0 = (2 * q) ^ (rl & 7);          // swizzled 16B chunks
                int c1 = (2 * q + 1) ^ (rl & 7);
                float4 lo = *(const float4*)&Afs[rl][c0 * 4];
                float4 hi = *(const float4*)&Afs[rl][c1 * 4];
                af[m] = cvt8(lo, hi);                 // pk cvt, hidden under MFMA
            }
#pragma unroll
            for (int n = 0; n < 4; ++n) {
                int rl = wc * 64 + n * 16 + r;
                bfr[n] = *reinterpret_cast<const short8*>(&Bsh[rl][q * 8]);
            }
#pragma unroll
            for (int m = 0; m < 4; ++m)
#pragma unroll
                for (int n = 0; n < 4; ++n)
                    acc[m][n] = __builtin_amdgcn_mfma_f32_16x16x32_bf16(
                        af[m], bfr[n], acc[m][n], 0, 0, 0);
        }
        __syncthreads();
    }

    // epilogue: + bo + query residual, f32 store
#pragma unroll
    for (int n = 0; n < 4; ++n) {
        int o = bx * 128 + wc * 64 + n * 16 + r;
        float bov = bo[o];
#pragma unroll
        for (int m = 0; m < 4; ++m) {
            int gb = brow + wr * 64 + m * 16 + q * 4;
#pragma unroll
            for (int j = 0; j < 4; ++j) {
                int grow = gb + j;
                out[(size_t)grow * D_MODEL + o] =
                    acc[m][n][j] + bov +
                    query[(size_t)(grow & (BATCH - 1)) * D_MODEL + o];
            }
        }
    }
}

extern "C" void kernel_launch(void* const* d_in, const int* in_sizes, int n_in,
                              void* d_out, int out_size, void* d_ws, size_t ws_size,
                              hipStream_t stream) {
    // Robust input classification by element count (falls back to dict order):
    int kv_i = 1, q_i = 0, bo_i = 6;
    int w_i[4] = {2, 3, 4, 5};
    int nw = 0;
    for (int i = 0; i < n_in; ++i) {
        long s = in_sizes[i];
        if (s == 33554432) kv_i = i;
        else if (s == 4194304) q_i = i;
        else if (s == 1024) bo_i = i;
        else if (s == 1048576 && nw < 4) w_i[nw++] = i;
    }
    const float* query = (const float*)d_in[q_i];
    const float* kv    = (const float*)d_in[kv_i];
    const float* Wv    = (const float*)d_in[w_i[2]];
    const float* Wo    = (const float*)d_in[w_i[3]];
    const float* bo    = (const float*)d_in[bo_i];
    short* Cw  = (short*)d_ws;              // 1024*1024 bf16 = 2 MB
    float* out = (float*)d_out;             // f32 output

    fuse_w_kernel<<<dim3(16, 16), dim3(256), 0, stream>>>(Wo, Wv, Cw);
    attn_gemm_kernel<<<dim3(2048), dim3(256), 0, stream>>>(kv, query, Cw, bo, out);
}

// Round 13
// 198.077 us; speedup vs baseline: 1.9976x; 1.1316x over previous
//
#include <hip/hip_runtime.h>
#include <hip/hip_bf16.h>

// out[m,b,:] = kv[m,b,:] @ W + bo + query[b,:],  W = (Wo@Wv) row o, col d
// (softmax over size-1 axis == 1 -> ones; q/k/Wq/Wk dead). f32 output.
// K1: Cw = Wo@Wv, MFMA bf16, 64x64 tiles, 256 blocks (~4us, proven r9).
// K2: OCCUPANCY ROUND. r7-r12 all plateau ~210us with every pipe idle and
//     Occupancy pinned at 22% (~2 blocks/CU): acc[4][4]=64 AGPR + ~104 VGPR
//     -> 2 waves/SIMD (regs halve waves at 64/128/256). Fix via TLP:
//     64x128 tile -> acc[2][4]=32 AGPR, __launch_bounds__(256,4) pins
//     allocation <=128 -> 4 waves/SIMD, 16KB LDS -> 4+ blocks/CU.
//     Staging identical to proven r12 (A f32 glds + XOR swizzle; B linear).

typedef __attribute__((ext_vector_type(4))) float f32x4;
typedef __attribute__((ext_vector_type(8))) short short8;

#define D_MODEL 1024
#define BATCH   4096
#define M_ROWS  32768   // 8 * 4096

__device__ __forceinline__ short f2bf(float f) {
    union { float f; unsigned u; } x; x.f = f;
    unsigned r = (x.u + 0x7fffu + ((x.u >> 16) & 1u)) >> 16;   // RNE
    return (short)r;
}

__device__ __forceinline__ unsigned bfpk(float lo, float hi) {
    __hip_bfloat162 h = __float22bfloat162_rn(make_float2(lo, hi));  // v_cvt_pk_bf16_f32
    unsigned u; __builtin_memcpy(&u, &h, 4); return u;
}

__device__ __forceinline__ short8 cvt8(float4 a, float4 b) {
    union { unsigned u[4]; short8 s; } r;
    r.u[0] = bfpk(a.x, a.y);
    r.u[1] = bfpk(a.z, a.w);
    r.u[2] = bfpk(b.x, b.y);
    r.u[3] = bfpk(b.z, b.w);
    return r.s;
}

// ---------------- Kernel 1: fuse weights Cw = Wo @ Wv (bf16, MFMA, 64x64) ----------------
__global__ __launch_bounds__(256) void fuse_w_kernel(
        const float* __restrict__ Wo, const float* __restrict__ Wv,
        short* __restrict__ Cw) {
    __shared__ __align__(16) short Ash[64][32];   // Wo tile  [o][e]
    __shared__ __align__(16) short Bsh[64][32];   // Wv tile transposed: [d][e]
    const int t = threadIdx.x;
    const int lane = t & 63;
    const int w = t >> 6;
    const int wr = w >> 1, wc = w & 1;
    const int brow = blockIdx.y * 64;   // o
    const int bcol = blockIdx.x * 64;   // d

    f32x4 acc[2][2];
#pragma unroll
    for (int m = 0; m < 2; ++m)
#pragma unroll
        for (int n = 0; n < 2; ++n) acc[m][n] = (f32x4)(0.0f);

    for (int kt = 0; kt < 32; ++kt) {
        const float* ga = Wo + (size_t)(brow + (t >> 2)) * D_MODEL + kt * 32 + (t & 3) * 8;
        float4 a0 = *(const float4*)ga;
        float4 a1 = *(const float4*)(ga + 4);
        float4 bv[2];
#pragma unroll
        for (int j = 0; j < 2; ++j) {
            int lin = j * 256 + t;
            int e = lin >> 4, c4 = lin & 15;
            bv[j] = *(const float4*)(Wv + (size_t)(kt * 32 + e) * D_MODEL + bcol + c4 * 4);
        }
        *reinterpret_cast<short8*>(&Ash[t >> 2][(t & 3) * 8]) = cvt8(a0, a1);
#pragma unroll
        for (int j = 0; j < 2; ++j) {
            int lin = j * 256 + t;
            int e = lin >> 4, c4 = lin & 15;
            int d = c4 * 4;
            Bsh[d + 0][e] = f2bf(bv[j].x);
            Bsh[d + 1][e] = f2bf(bv[j].y);
            Bsh[d + 2][e] = f2bf(bv[j].z);
            Bsh[d + 3][e] = f2bf(bv[j].w);
        }
        __syncthreads();
        {
            const int r = lane & 15, q = lane >> 4;
            short8 af[2], bfr[2];
#pragma unroll
            for (int m = 0; m < 2; ++m)
                af[m] = *reinterpret_cast<const short8*>(&Ash[wr * 32 + m * 16 + r][q * 8]);
#pragma unroll
            for (int n = 0; n < 2; ++n)
                bfr[n] = *reinterpret_cast<const short8*>(&Bsh[wc * 32 + n * 16 + r][q * 8]);
#pragma unroll
            for (int m = 0; m < 2; ++m)
#pragma unroll
                for (int n = 0; n < 2; ++n)
                    acc[m][n] = __builtin_amdgcn_mfma_f32_16x16x32_bf16(
                        af[m], bfr[n], acc[m][n], 0, 0, 0);
        }
        __syncthreads();
    }

    const int r = lane & 15, q = lane >> 4;
#pragma unroll
    for (int m = 0; m < 2; ++m)
#pragma unroll
        for (int n = 0; n < 2; ++n)
#pragma unroll
            for (int j = 0; j < 4; ++j) {
                int o = brow + wr * 32 + m * 16 + q * 4 + j;     // C/D: row=(l>>4)*4+j
                int d = bcol + wc * 32 + n * 16 + r;             //      col=l&15
                Cw[(size_t)o * D_MODEL + d] = f2bf(acc[m][n][j]);
            }
}

// ---------------- Kernel 2: out = kv @ Cw.T + bo + query — 64x128 tile, 4 waves/SIMD ----------------
__global__ __launch_bounds__(256, 4) void attn_gemm_kernel(
        const float* __restrict__ kv, const float* __restrict__ query,
        const short* __restrict__ Cw, const float* __restrict__ bo,
        float* __restrict__ out) {
    __shared__ __align__(16) float Afs[64][32];    // kv tile f32, XOR-swizzled (8 KB)
    __shared__ __align__(16) short Bsh[128][32];   // Cw tile bf16, linear (8 KB)
    const int t = threadIdx.x;
    const int lane = t & 63;
    const int w = t >> 6;
    const int wr = w >> 1, wc = w & 1;
    const int r = lane & 15, q = lane >> 4;

    // XCD swizzle: XCD = L % 8; the 8 o-tiles of one row-tile share an XCD
    // -> kv L2-reused 8x (proven r8: FETCH 574->141 MB).
    const int L = blockIdx.x;
    const int x = L & 7, j5 = L >> 3;
    const int bx = j5 & 7;                   // o-tile (0..7)
    const int rt = (j5 >> 3) * 8 + x;        // row-tile (0..511)
    const int brow = rt * 64;

    f32x4 acc[2][4];
#pragma unroll
    for (int m = 0; m < 2; ++m)
#pragma unroll
        for (int n = 0; n < 4; ++n) acc[m][n] = (f32x4)(0.0f);

    for (int kt = 0; kt < 32; ++kt) {
        // A: 64 rows x 32 f32 = 8 KB = 512 chunks of 16B, 2 glds issues.
        // LDS linear dest; SOURCE chunk pre-swizzled: cg = c ^ (row&7).
#pragma unroll
        for (int i = 0; i < 2; ++i) {
            int chunk = i * 256 + t;
            int rl = chunk >> 3, c = chunk & 7;
            int cg = c ^ (rl & 7);
            const float* g = kv + (size_t)(brow + rl) * D_MODEL + kt * 32 + cg * 4;
            __builtin_amdgcn_global_load_lds(
                (const __attribute__((address_space(1))) void*)g,
                (__attribute__((address_space(3))) void*)
                    ((char*)&Afs[0][0] + i * 4096 + w * 1024),
                16, 0, 0);
        }
        // B: 128 rows x 32 bf16 = 8 KB = 512 chunks of 16B, 2 glds, linear.
#pragma unroll
        for (int i = 0; i < 2; ++i) {
            int chunk = i * 256 + t;
            int rl = chunk >> 2, c8 = chunk & 3;
            const short* g = Cw + (size_t)(bx * 128 + rl) * D_MODEL + kt * 32 + c8 * 8;
            __builtin_amdgcn_global_load_lds(
                (const __attribute__((address_space(1))) void*)g,
                (__attribute__((address_space(3))) void*)
                    ((char*)&Bsh[0][0] + i * 4096 + w * 1024),
                16, 0, 0);
        }
        __syncthreads();
        {
            short8 af[2], bfr[4];
#pragma unroll
            for (int m = 0; m < 2; ++m) {
                int rl = wr * 32 + m * 16 + r;
                int c0 = (2 * q) ^ (rl & 7);          // swizzled 16B chunks
                int c1 = (2 * q + 1) ^ (rl & 7);
                float4 lo = *(const float4*)&Afs[rl][c0 * 4];
                float4 hi = *(const float4*)&Afs[rl][c1 * 4];
                af[m] = cvt8(lo, hi);                 // pk cvt under MFMA
            }
#pragma unroll
            for (int n = 0; n < 4; ++n) {
                int rl = wc * 64 + n * 16 + r;
                bfr[n] = *reinterpret_cast<const short8*>(&Bsh[rl][q * 8]);
            }
#pragma unroll
            for (int m = 0; m < 2; ++m)
#pragma unroll
                for (int n = 0; n < 4; ++n)
                    acc[m][n] = __builtin_amdgcn_mfma_f32_16x16x32_bf16(
                        af[m], bfr[n], acc[m][n], 0, 0, 0);
        }
        __syncthreads();
    }

    // epilogue: + bo + query residual, f32 store
#pragma unroll
    for (int n = 0; n < 4; ++n) {
        int o = bx * 128 + wc * 64 + n * 16 + r;
        float bov = bo[o];
#pragma unroll
        for (int m = 0; m < 2; ++m) {
            int gb = brow + wr * 32 + m * 16 + q * 4;
#pragma unroll
            for (int j = 0; j < 4; ++j) {
                int grow = gb + j;
                out[(size_t)grow * D_MODEL + o] =
                    acc[m][n][j] + bov +
                    query[(size_t)(grow & (BATCH - 1)) * D_MODEL + o];
            }
        }
    }
}

extern "C" void kernel_launch(void* const* d_in, const int* in_sizes, int n_in,
                              void* d_out, int out_size, void* d_ws, size_t ws_size,
                              hipStream_t stream) {
    // Robust input classification by element count (falls back to dict order):
    int kv_i = 1, q_i = 0, bo_i = 6;
    int w_i[4] = {2, 3, 4, 5};
    int nw = 0;
    for (int i = 0; i < n_in; ++i) {
        long s = in_sizes[i];
        if (s == 33554432) kv_i = i;
        else if (s == 4194304) q_i = i;
        else if (s == 1024) bo_i = i;
        else if (s == 1048576 && nw < 4) w_i[nw++] = i;
    }
    const float* query = (const float*)d_in[q_i];
    const float* kv    = (const float*)d_in[kv_i];
    const float* Wv    = (const float*)d_in[w_i[2]];
    const float* Wo    = (const float*)d_in[w_i[3]];
    const float* bo    = (const float*)d_in[bo_i];
    short* Cw  = (short*)d_ws;              // 1024*1024 bf16 = 2 MB
    float* out = (float*)d_out;             // f32 output

    fuse_w_kernel<<<dim3(16, 16), dim3(256), 0, stream>>>(Wo, Wv, Cw);
    attn_gemm_kernel<<<dim3(4096), dim3(256), 0, stream>>>(kv, query, Cw, bo, out);
}